// Round 11
// baseline (127.029 us; speedup 1.0000x reference)
//
#include <hip/hip_runtime.h>
#include <math.h>
#include <float.h>

#define NPix 3600
#define NC   256
#define NB   4
#define MCAP 768

typedef __attribute__((ext_vector_type(8))) _Float16 half8v;
typedef __attribute__((ext_vector_type(4))) float float4v;

__device__ __forceinline__ unsigned short f2h(float x) {
  _Float16 h = (_Float16)x;           // RTNE
  unsigned short u; __builtin_memcpy(&u, &h, 2); return u;
}
__device__ __forceinline__ float h2f(unsigned short u) {
  _Float16 h; __builtin_memcpy(&h, &u, 2); return (float)h;
}

// async global->LDS DMA, 16B per lane; LDS dest must be wave-uniform base
__device__ __forceinline__ void gld_lds16(const void* g, void* l) {
  __builtin_amdgcn_global_load_lds(
      (const __attribute__((address_space(1))) unsigned int*)g,
      (__attribute__((address_space(3))) unsigned int*)l, 16, 0, 0);
}

// ---------------- K0 (small-ws fallback only): column L2 norms --------------
__global__ __launch_bounds__(256) void k_colnorm(const float* __restrict__ feature,
                                                 float* __restrict__ colnorm) {
  int b = blockIdx.y;
  int n = blockIdx.x * 256 + threadIdx.x;
  if (n >= NPix) return;
  const float* feat = feature + (size_t)b * NC * NPix;
  float acc = 0.f;
#pragma unroll 8
  for (int c = 0; c < NC; ++c) {
    float v = feat[(size_t)c * NPix + n];
    acc += v * v;
  }
  colnorm[b * NPix + n] = sqrtf(acc);
}

// ---------------- top-12 fallback (block-wide iterative argmax, 1024 thr) ---
__device__ void block_top12(const float* __restrict__ p, int t,
                            float* s_rv, int* s_ri, int* s_chosen) {
  for (int k = 0; k < 12; ++k) {
    float best = -FLT_MAX;
    int bi = 0x7fffffff;
    for (int n = t; n < NPix; n += 1024) {
      bool excl = false;
      for (int j = 0; j < k; ++j)
        if (s_chosen[j] == n) excl = true;
      if (!excl) {
        float v = p[n];
        if (v > best || (v == best && n < bi)) { best = v; bi = n; }
      }
    }
    s_rv[t] = best; s_ri[t] = bi;
    __syncthreads();
    for (int d = 512; d > 0; d >>= 1) {
      if (t < d) {
        if (s_rv[t + d] > s_rv[t] ||
            (s_rv[t + d] == s_rv[t] && s_ri[t + d] < s_ri[t])) {
          s_rv[t] = s_rv[t + d]; s_ri[t] = s_ri[t + d];
        }
      }
      __syncthreads();
    }
    if (t == 0) s_chosen[k] = s_ri[0];
    __syncthreads();
  }
  if (t == 0) {
    for (int a = 1; a < 12; ++a) {
      int key = s_chosen[a]; int j = a - 1;
      while (j >= 0 && s_chosen[j] > key) { s_chosen[j + 1] = s_chosen[j]; --j; }
      s_chosen[j + 1] = key;
    }
  }
  __syncthreads();
}

// ---------------- K1: masks + deterministic compaction (ballot scan) --------
__global__ __launch_bounds__(1024) void k_mask(const float* __restrict__ mask_q,
                                               unsigned char* __restrict__ fgm,
                                               unsigned char* __restrict__ bgm,
                                               int* __restrict__ bgsel,
                                               int* __restrict__ cnts) {
  int b = blockIdx.x;
  int t = threadIdx.x;
  int wv = t >> 6, l = t & 63;   // 16 waves
  const float* pred_bg = mask_q + (size_t)b * 2 * NPix;
  const float* pred_fg = pred_bg + NPix;

  __shared__ int   s_wtot[16];
  __shared__ int   s_base[2];
  __shared__ float s_rv[1024];
  __shared__ int   s_ri[1024];
  __shared__ int   s_chosen[12];

  if (t == 0) { s_base[0] = 0; s_base[1] = 0; }
  __syncthreads();

  unsigned long long lmask = (1ull << l) - 1ull;

  for (int chunk = 0; chunk < NPix; chunk += 1024) {
    int n = chunk + t;
    int fgf = 0, bgf = 0;
    if (n < NPix) {
      fgf = pred_fg[n] > 0.5f ? 1 : 0;
      bgf = pred_bg[n] > 0.8f ? 1 : 0;
      fgm[b * NPix + n] = (unsigned char)fgf;
      bgm[b * NPix + n] = (unsigned char)bgf;
    }
    unsigned long long fb = __ballot(fgf != 0);
    unsigned long long bb = __ballot(bgf != 0);
    if (l == 0) s_wtot[wv] = __popcll(fb) | (__popcll(bb) << 16);
    __syncthreads();
    int fsum = 0, bsum = 0, bpre = 0;
#pragma unroll
    for (int w = 0; w < 16; ++w) {
      int v = s_wtot[w];
      if (w < wv) bpre += (v >> 16);
      fsum += v & 0xffff; bsum += (v >> 16);
    }
    if (bgf) {
      int pos = s_base[1] + bpre + (int)__popcll(bb & lmask);
      bgsel[b * NPix + pos] = n;
    }
    __syncthreads();
    if (t == 0) { s_base[0] += fsum; s_base[1] += bsum; }
    __syncthreads();
  }
  int fgcnt = s_base[0];
  int bgcnt = s_base[1];

  if (fgcnt == 0) {
    block_top12(pred_fg, t, s_rv, s_ri, s_chosen);
    if (t < 12) fgm[b * NPix + s_chosen[t]] = 1;
    fgcnt = 12;
    __syncthreads();
  }
  if (bgcnt == 0) {
    block_top12(pred_bg, t, s_rv, s_ri, s_chosen);
    if (t < 12) {
      bgm[b * NPix + s_chosen[t]] = 1;
      bgsel[b * NPix + t] = s_chosen[t];
    }
    bgcnt = 12;
    __syncthreads();
  }
  if (t == 0) { cnts[b] = fgcnt; cnts[4 + b] = bgcnt; }
}

// ---------------- K2 (small-ws fallback only): prototypes -------------------
__global__ __launch_bounds__(256) void k_proto(const float* __restrict__ feature,
                                               const unsigned char* __restrict__ fgm,
                                               const unsigned char* __restrict__ bgm,
                                               const int* __restrict__ cnts,
                                               float* __restrict__ out,
                                               float* __restrict__ bgproto) {
  int c = blockIdx.x, b = blockIdx.y, t = threadIdx.x;
  const float* frow = feature + ((size_t)b * NC + c) * NPix;
  float fs = 0.f, bs = 0.f;
  for (int n = t; n < NPix; n += 256) {
    float v = frow[n];
    fs += v * (float)fgm[b * NPix + n];
    bs += v * (float)bgm[b * NPix + n];
  }
  __shared__ float s1[256], s2[256];
  s1[t] = fs; s2[t] = bs;
  __syncthreads();
  for (int d = 128; d > 0; d >>= 1) {
    if (t < d) { s1[t] += s1[t + d]; s2[t] += s2[t + d]; }
    __syncthreads();
  }
  if (t == 0) {
    out[b * NC + c]     = s1[0] / (float)cnts[b];
    bgproto[b * NC + c] = s2[0] / (float)cnts[4 + b];
  }
}

// ---------------- K3: fused colnorm + fp16 pack + proto (single feature read)
// Phase A loads the block's full 64px x 256ch working set into registers
// (float4 raw[16], statically indexed) while accumulating sum-of-squares.
// Phase B writes traw/tl per 64-ch chunk straight from registers (wave cs
// holds exactly chunk cs's channels) -- no feature re-read.
__global__ __launch_bounds__(256) void k_normpack(const float* __restrict__ feature,
                                                  const unsigned char* __restrict__ fgm,
                                                  const unsigned char* __restrict__ bgm,
                                                  float* __restrict__ colnorm,
                                                  unsigned short* __restrict__ Qf,
                                                  float* __restrict__ pp) {
  int b = blockIdx.y, nt = blockIdx.x, t = threadIdx.x;
  int n0 = nt * 64;
  __shared__ float s_sq[16][68];
  __shared__ float s_inv[64];
  __shared__ float s_fg[64], s_bg[64];
  __shared__ unsigned int tl[64][65];
  __shared__ float traw[64][65];
  __shared__ float s_red[2][4][64];
  const float* fb = feature + (size_t)b * NC * NPix;

  // phase A: load into regs + sum of squares
  int p4 = t & 15, cq = t >> 4;
  float4 raw[16];
  float sq0 = 0.f, sq1 = 0.f, sq2 = 0.f, sq3 = 0.f;
  if (n0 + 64 <= NPix) {
#pragma unroll
    for (int j = 0; j < 16; ++j) {
      float4 v = *(const float4*)(fb + (size_t)(cq * 16 + j) * NPix + n0 + p4 * 4);
      raw[j] = v;
      sq0 += v.x * v.x; sq1 += v.y * v.y; sq2 += v.z * v.z; sq3 += v.w * v.w;
    }
  } else {
#pragma unroll
    for (int j = 0; j < 16; ++j) {
      size_t base = (size_t)(cq * 16 + j) * NPix;
      int n = n0 + p4 * 4;
      float4 v;
      v.x = (n + 0 < NPix) ? fb[base + n + 0] : 0.f;
      v.y = (n + 1 < NPix) ? fb[base + n + 1] : 0.f;
      v.z = (n + 2 < NPix) ? fb[base + n + 2] : 0.f;
      v.w = (n + 3 < NPix) ? fb[base + n + 3] : 0.f;
      raw[j] = v;
      sq0 += v.x * v.x; sq1 += v.y * v.y; sq2 += v.z * v.z; sq3 += v.w * v.w;
    }
  }
  s_sq[cq][p4 * 4 + 0] = sq0;
  s_sq[cq][p4 * 4 + 1] = sq1;
  s_sq[cq][p4 * 4 + 2] = sq2;
  s_sq[cq][p4 * 4 + 3] = sq3;
  __syncthreads();
  if (t < 64) {
    float acc = 0.f;
#pragma unroll
    for (int q = 0; q < 16; ++q) acc += s_sq[q][t];
    float nrm = sqrtf(acc);
    int n = n0 + t;
    s_inv[t] = (n < NPix) ? 1.f / nrm : 0.f;
    if (n < NPix) colnorm[b * NPix + n] = nrm;
    s_fg[t] = (n < NPix) ? (float)fgm[b * NPix + n] : 0.f;
    s_bg[t] = (n < NPix) ? (float)bgm[b * NPix + n] : 0.f;
  }
  __syncthreads();

  // phase B: per 64-ch chunk, write traw/tl from registers
  unsigned short* QfB = Qf + (size_t)b * NPix * NC;
  int clbase = (cq & 3) * 16;
  int nlb = p4 * 4;
  float inv0 = s_inv[nlb + 0], inv1 = s_inv[nlb + 1];
  float inv2 = s_inv[nlb + 2], inv3 = s_inv[nlb + 3];
  for (int cs = 0; cs < 4; ++cs) {
    int c0 = cs * 64;
    if ((cq >> 2) == cs) {     // wave cs holds channels [cs*64, cs*64+64)
#pragma unroll
      for (int j = 0; j < 16; ++j) {
        int cl = clbase + j;
        float4 v = raw[j];
        traw[cl][nlb + 0] = v.x;  tl[cl][nlb + 0] = (unsigned int)f2h(v.x * inv0);
        traw[cl][nlb + 1] = v.y;  tl[cl][nlb + 1] = (unsigned int)f2h(v.y * inv1);
        traw[cl][nlb + 2] = v.z;  tl[cl][nlb + 2] = (unsigned int)f2h(v.z * inv2);
        traw[cl][nlb + 3] = v.w;  tl[cl][nlb + 3] = (unsigned int)f2h(v.w * inv3);
      }
    }
    __syncthreads();
    // coalesced fp16 pack (2 ch per u32)
#pragma unroll
    for (int i = 0; i < 8; ++i) {
      int idx = t + 256 * i;
      int n = idx >> 5;
      int cp = idx & 31;
      int row = n0 + n;
      if (row < NPix) {
        unsigned int u = (tl[2 * cp][n] & 0xffffu) | (tl[2 * cp + 1][n] << 16);
        *(unsigned int*)&QfB[(size_t)row * NC + c0 + 2 * cp] = u;
      }
    }
    // proto partials (exact raw values, fixed order)
    {
      int cl = t & 63, pq = t >> 6;
      float pf = 0.f, pb = 0.f;
#pragma unroll
      for (int k = 0; k < 16; ++k) {
        int p = pq * 16 + k;
        float feat = traw[cl][p];
        pf += feat * s_fg[p];
        pb += feat * s_bg[p];
      }
      s_red[0][pq][cl] = pf;
      s_red[1][pq][cl] = pb;
    }
    __syncthreads();
    if (t < 128) {
      int m = t >> 6, cl = t & 63;
      float s = s_red[m][0][cl] + s_red[m][1][cl] + s_red[m][2][cl] + s_red[m][3][cl];
      pp[((size_t)(b * 57 + nt) * 2 + m) * 256 + c0 + cl] = s;
    }
    __syncthreads();
  }
}

// ---------------- K4: merged GEMM1 + V^T build + proto reduce ---------------
// Flattened grid.x per batch: [0,174) GEMM1 (rt=x%29, jt=x/29);
// [174,222) V^T build (u=x-174: jt=u>>2, cs=u&3); x==222 proto reduce.
__global__ __launch_bounds__(256) void k_vg(const unsigned short* __restrict__ Qf,
                                            const float* __restrict__ colnorm,
                                            const int* __restrict__ cnts,
                                            const int* __restrict__ bgsel,
                                            unsigned short* __restrict__ Vg,
                                            const float* __restrict__ pp,
                                            float* __restrict__ out,
                                            float* __restrict__ bgproto,
                                            unsigned short* __restrict__ wbuf,
                                            float* __restrict__ wpart) {
  int b = blockIdx.z;
  int x = blockIdx.x;
  int t = threadIdx.x;

  __shared__ __align__(16) char smem[32768];

  if (x == 222) {                 // ---- proto reduce ----
    int c = t;
    float f = 0.f, g = 0.f;
    for (int nt = 0; nt < 57; ++nt) {
      const float* base = pp + (size_t)(b * 57 + nt) * 2 * 256;
      f += base[c];
      g += base[256 + c];
    }
    out[b * NC + c]     = f / (float)cnts[b];
    bgproto[b * NC + c] = g / (float)cnts[4 + b];
    return;
  }

  int M = cnts[4 + b];
  if (M > MCAP) return;

  if (x >= 174) {                 // ---- V^T fp16 build ----
    int u = x - 174;
    int jt = u >> 2, cs = u & 3;
    int j0 = jt * 64, c0 = cs * 64;
    unsigned short* tl = (unsigned short*)smem;   // [64][73]
    const size_t qoff = (size_t)b * NPix * NC;
#pragma unroll
    for (int i = 0; i < 16; ++i) {
      int idx = t + 256 * i; int j = idx >> 6, ch = idx & 63;
      int jg = j0 + j;
      float v = 0.f;
      if (jg < M) {
        int src = bgsel[b * NPix + jg];
        v = h2f(Qf[qoff + (size_t)src * NC + c0 + ch]) * colnorm[b * NPix + src];
      }
      tl[j * 73 + ch] = f2h(v);
    }
    __syncthreads();
#pragma unroll
    for (int i = 0; i < 16; ++i) {
      int idx = t + 256 * i; int ch = idx >> 6, j = idx & 63;
      Vg[((size_t)b * NC + c0 + ch) * MCAP + j0 + j] = tl[j * 73 + ch];
    }
    return;
  }

  // ---- GEMM1: 128x128 tile, gld_lds + source-side XOR swizzle ----
  int rt = x % 29, jt = x / 29;
  if (jt * 128 >= M) return;
  int wv = t >> 6, l = t & 63;
  int n0 = rt * 128, j0 = jt * 128;

  unsigned short* Ah = (unsigned short*)smem;                // [128][64]
  unsigned short* Bh = (unsigned short*)(smem + 16384);      // [128][64]

  const unsigned short* QfB = Qf + (size_t)b * NPix * NC;

  size_t asrc[4];
  int    aslt[4];
#pragma unroll
  for (int i = 0; i < 4; ++i) {
    int u = i * 256 + wv * 64 + l;           // 0..1023
    int r = u >> 3, sl = u & 7;
    int grow = n0 + r; if (grow > NPix - 1) grow = NPix - 1;
    asrc[i] = (size_t)grow * NC;
    aslt[i] = (sl ^ (r & 7)) << 3;
  }
  size_t bsrc[4];
  int    bslt[4];
#pragma unroll
  for (int i = 0; i < 4; ++i) {
    int u = i * 256 + wv * 64 + l;           // 0..1023
    int r = u >> 3, sl = u & 7;
    int jg = j0 + r;
    int src = (jg < M) ? bgsel[b * NPix + jg] : 0;
    bsrc[i] = (size_t)src * NC;
    bslt[i] = (sl ^ (r & 7)) << 3;
  }

  int lr = l & 15;
  int lk = l >> 4;

  float4v acc[2][8];
#pragma unroll
  for (int rf = 0; rf < 2; ++rf)
#pragma unroll
    for (int cf = 0; cf < 8; ++cf) { float4v z = {0.f,0.f,0.f,0.f}; acc[rf][cf] = z; }

  for (int cc = 0; cc < 4; ++cc) {
    int cbase = cc * 64;
#pragma unroll
    for (int i = 0; i < 4; ++i) {
      int ldso = (i * 256 + wv * 64) * 16;
      gld_lds16(QfB + asrc[i] + cbase + aslt[i], (char*)Ah + ldso);
    }
#pragma unroll
    for (int i = 0; i < 4; ++i) {
      int ldso = (i * 256 + wv * 64) * 16;
      gld_lds16(QfB + bsrc[i] + cbase + bslt[i], (char*)Bh + ldso);
    }
    __syncthreads();   // drains vmcnt -> DMA complete

#pragma unroll
    for (int kk = 0; kk < 2; ++kk) {
      int kslot = kk * 4 + lk;
      half8v ah[2];
#pragma unroll
      for (int rf = 0; rf < 2; ++rf) {
        int r = wv * 32 + rf * 16 + lr;
        int s = (kslot ^ (r & 7)) << 3;
        ah[rf] = *(const half8v*)&Ah[r * 64 + s];
      }
#pragma unroll
      for (int cf = 0; cf < 8; ++cf) {
        int j = cf * 16 + lr;
        int s = (kslot ^ (j & 7)) << 3;
        half8v bh = *(const half8v*)&Bh[j * 64 + s];
#pragma unroll
        for (int rf = 0; rf < 2; ++rf)
          acc[rf][cf] = __builtin_amdgcn_mfma_f32_16x16x32_f16(ah[rf], bh, acc[rf][cf], 0, 0, 0);
      }
    }
    __syncthreads();   // before next-chunk overwrite
  }

  // epilogue: w = exp(2s-2) -> fp16; store + per-row partial sums
  float rs[2][4];
#pragma unroll
  for (int rf = 0; rf < 2; ++rf)
#pragma unroll
    for (int i = 0; i < 4; ++i) rs[rf][i] = 0.f;

#pragma unroll
  for (int rf = 0; rf < 2; ++rf)
#pragma unroll
    for (int cf = 0; cf < 8; ++cf)
#pragma unroll
      for (int i = 0; i < 4; ++i) {
        int row = n0 + wv * 32 + rf * 16 + lk * 4 + i;
        int j = j0 + cf * 16 + lr;
        float s = acc[rf][cf][i];
        unsigned short w16 = (j < M) ? f2h(__expf(2.f * s - 2.f)) : (unsigned short)0;
        if (row < NPix)
          wbuf[((size_t)b * NPix + row) * MCAP + j] = w16;
        rs[rf][i] += h2f(w16);
      }

#pragma unroll
  for (int rf = 0; rf < 2; ++rf)
#pragma unroll
    for (int i = 0; i < 4; ++i) {
      float v = rs[rf][i];
      v += __shfl_xor(v, 1);
      v += __shfl_xor(v, 2);
      v += __shfl_xor(v, 4);
      v += __shfl_xor(v, 8);
      int row = n0 + wv * 32 + rf * 16 + lk * 4 + i;
      if (lr == 0 && row < NPix)
        wpart[((size_t)b * NPix + row) * 12 + jt] = v;
    }
}

// ---------------- K5: GEMM2 fp16 + lsum + epilogue + gated fallback attn ----
// Flattened grid.x per batch: [0,58) GEMM2 (rt=x%29, cs=x/29);
// [58,283) fallback self-normalizing attention (only when M > MCAP).
__global__ __launch_bounds__(256, 3) void k_gemm2e(const unsigned short* __restrict__ wbuf,
                                                   const unsigned short* __restrict__ Vg,
                                                   const int* __restrict__ cnts,
                                                   const float* __restrict__ wpart,
                                                   const float* __restrict__ bgproto,
                                                   const float* __restrict__ feature,
                                                   const float* __restrict__ colnorm,
                                                   const int* __restrict__ bgsel,
                                                   float* __restrict__ out) {
  int b = blockIdx.z; int M = cnts[4 + b];
  int x = blockIdx.x;
  int t = threadIdx.x;

  __shared__ __align__(16) char smem[34816];   // 34 KB union

  if (x >= 58) {
    // ---- fallback attention (M > MCAP only) ----
    if (M <= MCAP) return;
    int tile = x - 58;
    int rl  = t >> 4;
    int l16 = t & 15;
    int row = tile * 16 + rl;
    const float* feat = feature + (size_t)b * NC * NPix;
    float* s_k  = (float*)smem;          // [32][256]
    float* s_vn = (float*)(smem + 32768);

    float inv_n = 1.f / colnorm[b * NPix + row];
    float q[16];
#pragma unroll
    for (int k = 0; k < 4; ++k)
#pragma unroll
      for (int i = 0; i < 4; ++i) {
        int c = l16 * 4 + 64 * k + i;
        q[k * 4 + i] = feat[(size_t)c * NPix + row] * inv_n;
      }

    float l_acc = 0.f;
    float O[16];
#pragma unroll
    for (int i = 0; i < 16; ++i) O[i] = 0.f;

    for (int kt = 0; kt < M; kt += 32) {
      int jmax = min(32, M - kt);
      __syncthreads();
      for (int u = t; u < 32 * 64; u += 256) {
        int jj = u >> 6;
        int cc = (u & 63) << 2;
        if (jj < jmax) {
          int src = bgsel[b * NPix + kt + jj];
          float inv = 1.f / colnorm[b * NPix + src];
          float4 v;
          v.x = feat[(size_t)(cc + 0) * NPix + src] * inv;
          v.y = feat[(size_t)(cc + 1) * NPix + src] * inv;
          v.z = feat[(size_t)(cc + 2) * NPix + src] * inv;
          v.w = feat[(size_t)(cc + 3) * NPix + src] * inv;
          *(float4*)&s_k[jj * 256 + cc] = v;
        }
      }
      if (t < 32)
        s_vn[t] = (t < jmax) ? colnorm[b * NPix + bgsel[b * NPix + kt + t]] : 0.f;
      __syncthreads();

      for (int j = 0; j < jmax; ++j) {
        float kv[16];
        float s = 0.f;
#pragma unroll
        for (int k = 0; k < 4; ++k) {
          float4 v4 = *(const float4*)&s_k[j * 256 + l16 * 4 + 64 * k];
          kv[k * 4 + 0] = v4.x; kv[k * 4 + 1] = v4.y;
          kv[k * 4 + 2] = v4.z; kv[k * 4 + 3] = v4.w;
          s += q[k * 4 + 0] * v4.x + q[k * 4 + 1] * v4.y +
               q[k * 4 + 2] * v4.z + q[k * 4 + 3] * v4.w;
        }
        s += __shfl_xor(s, 1);
        s += __shfl_xor(s, 2);
        s += __shfl_xor(s, 4);
        s += __shfl_xor(s, 8);
        float e = __expf(2.f * s - 2.f);
        l_acc += e;
        float ev = e * s_vn[j];
#pragma unroll
        for (int i = 0; i < 16; ++i) O[i] += ev * kv[i];
      }
    }

    float inv_l = 1.f / l_acc;
    float* outBP = out + NB * NC;
    const float* bp = bgproto + b * NC;
#pragma unroll
    for (int k = 0; k < 4; ++k)
#pragma unroll
      for (int i = 0; i < 4; ++i) {
        int c = l16 * 4 + 64 * k + i;
        outBP[((size_t)b * NC + c) * NPix + row] =
            bp[c] * 0.3f + O[k * 4 + i] * inv_l * 0.7f;
      }
    return;
  }

  // ---- GEMM2 path ----
  if (M > MCAP) return;
  int rt = x % 29, cs = x / 29;
  int wv = t >> 6, l = t & 63;
  int n0 = rt * 128, c0 = cs * 128;
  int arow0 = n0 + wv * 32 + (l & 15);
  int arow1 = arow0 + 16;
  if (arow0 > NPix - 1) arow0 = NPix - 1;
  if (arow1 > NPix - 1) arow1 = NPix - 1;
  const unsigned short* wr0 = wbuf + ((size_t)b * NPix + arow0) * MCAP + (l >> 4) * 8;
  const unsigned short* wr1 = wbuf + ((size_t)b * NPix + arow1) * MCAP + (l >> 4) * 8;
  const unsigned short* vb  = Vg + ((size_t)b * NC + c0 + (l & 15)) * MCAP + (l >> 4) * 8;

  float* trans  = (float*)smem;                 // [64][129] = 33024 B
  float* s_linv = (float*)(smem + 33024);       // [128]
  float* s_bp   = (float*)(smem + 33536);       // [128]

  float4v acc[2][8];
#pragma unroll
  for (int rf = 0; rf < 2; ++rf)
#pragma unroll
    for (int cf = 0; cf < 8; ++cf) { float4v z = {0.f,0.f,0.f,0.f}; acc[rf][cf] = z; }

  int nkk = (M + 31) >> 5;
  for (int kk = 0; kk < nkk; ++kk) {
    half8v a0 = *(const half8v*)(wr0 + kk * 32);
    half8v a1 = *(const half8v*)(wr1 + kk * 32);
#pragma unroll
    for (int cf = 0; cf < 8; ++cf) {
      half8v bv = *(const half8v*)(vb + (size_t)cf * 16 * MCAP + kk * 32);
      acc[0][cf] = __builtin_amdgcn_mfma_f32_16x16x32_f16(a0, bv, acc[0][cf], 0, 0, 0);
      acc[1][cf] = __builtin_amdgcn_mfma_f32_16x16x32_f16(a1, bv, acc[1][cf], 0, 0, 0);
    }
  }

  // fused lsum: reduce j-tile partials per row (128-wide tiles)
  if (t < 128) {
    int row = n0 + t;
    if (row < NPix) {
      const float* wp = wpart + ((size_t)b * NPix + row) * 12;
      int njt = (M + 127) >> 7;
      float s = 0.f;
      for (int j = 0; j < njt; ++j) s += wp[j];
      s_linv[t] = 1.f / s;
    } else s_linv[t] = 0.f;
    s_bp[t] = bgproto[b * NC + c0 + t];
  }

  int g = l >> 4;
  float* outBP = out + NB * NC;
#pragma unroll
  for (int half = 0; half < 2; ++half) {
    __syncthreads();   // half0: covers s_linv/s_bp; half1: trans reads done
#pragma unroll
    for (int cfl = 0; cfl < 4; ++cfl) {
      int cf = half * 4 + cfl;
#pragma unroll
      for (int rf = 0; rf < 2; ++rf)
#pragma unroll
        for (int i = 0; i < 4; ++i) {
          int c_l = cfl * 16 + (l & 15);
          int n_l = wv * 32 + rf * 16 + g * 4 + i;
          trans[c_l * 129 + n_l] = acc[rf][cf][i];
        }
    }
    __syncthreads();
#pragma unroll
    for (int it = 0; it < 8; ++it) {
      int idx = t + 256 * it;       // 0..2047
      int c_l = idx >> 5;           // 0..63
      int q   = idx & 31;           // n-quad
      int n   = n0 + q * 4;
      if (n < NPix) {               // NPix%4==0 -> whole quad in range
        float bpv = s_bp[half * 64 + c_l];
        float4 o;
        o.x = bpv * 0.3f + trans[c_l * 129 + q * 4 + 0] * s_linv[q * 4 + 0] * 0.7f;
        o.y = bpv * 0.3f + trans[c_l * 129 + q * 4 + 1] * s_linv[q * 4 + 1] * 0.7f;
        o.z = bpv * 0.3f + trans[c_l * 129 + q * 4 + 2] * s_linv[q * 4 + 2] * 0.7f;
        o.w = bpv * 0.3f + trans[c_l * 129 + q * 4 + 3] * s_linv[q * 4 + 3] * 0.7f;
        *(float4*)&outBP[((size_t)b * NC + c0 + half * 64 + c_l) * NPix + n] = o;
      }
    }
  }
}

// ---------------- small-ws fallback: self-normalizing fp32 attention --------
__global__ __launch_bounds__(256) void k_attn(const float* __restrict__ feature,
                                              const float* __restrict__ colnorm,
                                              const int* __restrict__ cnts,
                                              const int* __restrict__ bgsel,
                                              const float* __restrict__ bgproto,
                                              float* __restrict__ out) {
  int b = blockIdx.y;
  int M = cnts[4 + b];
  int tile = blockIdx.x;
  int t = threadIdx.x;
  int rl  = t >> 4;
  int l16 = t & 15;
  int row = tile * 16 + rl;
  const float* feat = feature + (size_t)b * NC * NPix;

  __shared__ float s_k[32][NC];
  __shared__ float s_vn[32];

  float inv_n = 1.f / colnorm[b * NPix + row];
  float q[16];
#pragma unroll
  for (int k = 0; k < 4; ++k)
#pragma unroll
    for (int i = 0; i < 4; ++i) {
      int c = l16 * 4 + 64 * k + i;
      q[k * 4 + i] = feat[(size_t)c * NPix + row] * inv_n;
    }

  float l_acc = 0.f;
  float O[16];
#pragma unroll
  for (int i = 0; i < 16; ++i) O[i] = 0.f;

  for (int kt = 0; kt < M; kt += 32) {
    int jmax = min(32, M - kt);
    __syncthreads();
    for (int u = t; u < 32 * 64; u += 256) {
      int jj = u >> 6;
      int cc = (u & 63) << 2;
      if (jj < jmax) {
        int src = bgsel[b * NPix + kt + jj];
        float inv = 1.f / colnorm[b * NPix + src];
        float4 v;
        v.x = feat[(size_t)(cc + 0) * NPix + src] * inv;
        v.y = feat[(size_t)(cc + 1) * NPix + src] * inv;
        v.z = feat[(size_t)(cc + 2) * NPix + src] * inv;
        v.w = feat[(size_t)(cc + 3) * NPix + src] * inv;
        *(float4*)&s_k[jj][cc] = v;
      }
    }
    if (t < 32)
      s_vn[t] = (t < jmax) ? colnorm[b * NPix + bgsel[b * NPix + kt + t]] : 0.f;
    __syncthreads();

    for (int j = 0; j < jmax; ++j) {
      float kv[16];
      float s = 0.f;
#pragma unroll
      for (int k = 0; k < 4; ++k) {
        float4 v4 = *(const float4*)&s_k[j][l16 * 4 + 64 * k];
        kv[k * 4 + 0] = v4.x; kv[k * 4 + 1] = v4.y;
        kv[k * 4 + 2] = v4.z; kv[k * 4 + 3] = v4.w;
        s += q[k * 4 + 0] * v4.x + q[k * 4 + 1] * v4.y +
             q[k * 4 + 2] * v4.z + q[k * 4 + 3] * v4.w;
      }
      s += __shfl_xor(s, 1);
      s += __shfl_xor(s, 2);
      s += __shfl_xor(s, 4);
      s += __shfl_xor(s, 8);
      float e = __expf(2.f * s - 2.f);
      l_acc += e;
      float ev = e * s_vn[j];
#pragma unroll
      for (int i = 0; i < 16; ++i) O[i] += ev * kv[i];
    }
  }

  float inv_l = 1.f / l_acc;
  float* outBP = out + NB * NC;
  const float* bp = bgproto + b * NC;
#pragma unroll
  for (int k = 0; k < 4; ++k)
#pragma unroll
    for (int i = 0; i < 4; ++i) {
      int c = l16 * 4 + 64 * k + i;
      outBP[((size_t)b * NC + c) * NPix + row] =
          bp[c] * 0.3f + O[k * 4 + i] * inv_l * 0.7f;
    }
}

// ---------------------------------------------------------------------------
extern "C" void kernel_launch(void* const* d_in, const int* in_sizes, int n_in,
                              void* d_out, int out_size, void* d_ws, size_t ws_size,
                              hipStream_t stream) {
  const float* feature = (const float*)d_in[0];
  const float* mask_q  = (const float*)d_in[1];
  float* out = (float*)d_out;
  char* ws = (char*)d_ws;

  const size_t BIG_NEED = 32428160ULL;
  if (ws_size >= BIG_NEED) {
    // big-mode carve (all offsets 16B-aligned, sizes in BYTES):
    float* colnorm   = (float*)(ws + 0);          //    57,600
    float* bgproto   = (float*)(ws + 115200);     //     4,096
    int*   cnts      = (int*)  (ws + 119296);     //       256 slot
    int*   bgsel     = (int*)  (ws + 119552);     //    57,600 -> 177,152
    unsigned char* fgm = (unsigned char*)(ws + 177152);    // 14,400
    unsigned char* bgm = (unsigned char*)(ws + 191552);    // 14,400 -> 205,952
    float* pp        = (float*)(ws + 205952);     //   466,944 -> 672,896
    unsigned short* Vg  = (unsigned short*)(ws + 672896);   //  1,572,864 -> 2,245,760
    unsigned short* Qf  = (unsigned short*)(ws + 2245760);  //  7,372,800 -> 9,618,560
    unsigned short* wbuf = (unsigned short*)(ws + 9618560); // 22,118,400 -> 31,736,960
    float* wpart     = (float*)(ws + 31736960);   //   691,200 -> 32,428,160

    k_mask    <<<NB,               1024, 0, stream>>>(mask_q, fgm, bgm, bgsel, cnts);
    k_normpack<<<dim3(57, NB),     256, 0, stream>>>(feature, fgm, bgm, colnorm, Qf, pp);
    k_vg      <<<dim3(223, 1, NB), 256, 0, stream>>>(Qf, colnorm, cnts, bgsel, Vg,
                                                     pp, out, bgproto, wbuf, wpart);
    k_gemm2e  <<<dim3(283, 1, NB), 256, 0, stream>>>(wbuf, Vg, cnts, wpart, bgproto,
                                                     feature, colnorm, bgsel, out);
  } else {
    // small-ws fallback: simple kernels, self-normalizing attention
    float* colnorm  = (float*)(ws + 0);
    float* bgproto  = (float*)(ws + 115200);
    int*   cnts     = (int*)  (ws + 119296);
    int*   bgsel    = (int*)  (ws + 119552);
    unsigned char* fgm = (unsigned char*)(ws + 177152);
    unsigned char* bgm = (unsigned char*)(ws + 191552);

    k_colnorm<<<dim3(15, NB), 256, 0, stream>>>(feature, colnorm);
    k_mask   <<<NB,           1024, 0, stream>>>(mask_q, fgm, bgm, bgsel, cnts);
    k_proto  <<<dim3(NC, NB), 256, 0, stream>>>(feature, fgm, bgm, cnts, out, bgproto);
    k_attn   <<<dim3(225, NB),256, 0, stream>>>(feature, colnorm, cnts, bgsel,
                                                bgproto, out);
  }
}

// Round 12
// 81.927 us; speedup vs baseline: 1.5505x; 1.5505x over previous
//
#include <hip/hip_runtime.h>
#include <math.h>
#include <float.h>

#define NPix 3600
#define NC   256
#define NB   4
#define MCAP 768

typedef __attribute__((ext_vector_type(8))) _Float16 half8v;
typedef __attribute__((ext_vector_type(4))) float float4v;

__device__ __forceinline__ unsigned short f2h(float x) {
  _Float16 h = (_Float16)x;           // RTNE
  unsigned short u; __builtin_memcpy(&u, &h, 2); return u;
}
__device__ __forceinline__ float h2f(unsigned short u) {
  _Float16 h; __builtin_memcpy(&h, &u, 2); return (float)h;
}

// async global->LDS DMA, 16B per lane; LDS dest must be wave-uniform base
__device__ __forceinline__ void gld_lds16(const void* g, void* l) {
  __builtin_amdgcn_global_load_lds(
      (const __attribute__((address_space(1))) unsigned int*)g,
      (__attribute__((address_space(3))) unsigned int*)l, 16, 0, 0);
}

// ---------------- K0 (small-ws fallback only): column L2 norms --------------
__global__ __launch_bounds__(256) void k_colnorm(const float* __restrict__ feature,
                                                 float* __restrict__ colnorm) {
  int b = blockIdx.y;
  int n = blockIdx.x * 256 + threadIdx.x;
  if (n >= NPix) return;
  const float* feat = feature + (size_t)b * NC * NPix;
  float acc = 0.f;
#pragma unroll 8
  for (int c = 0; c < NC; ++c) {
    float v = feat[(size_t)c * NPix + n];
    acc += v * v;
  }
  colnorm[b * NPix + n] = sqrtf(acc);
}

// ---------------- top-12 fallback (block-wide iterative argmax, 1024 thr) ---
__device__ void block_top12(const float* __restrict__ p, int t,
                            float* s_rv, int* s_ri, int* s_chosen) {
  for (int k = 0; k < 12; ++k) {
    float best = -FLT_MAX;
    int bi = 0x7fffffff;
    for (int n = t; n < NPix; n += 1024) {
      bool excl = false;
      for (int j = 0; j < k; ++j)
        if (s_chosen[j] == n) excl = true;
      if (!excl) {
        float v = p[n];
        if (v > best || (v == best && n < bi)) { best = v; bi = n; }
      }
    }
    s_rv[t] = best; s_ri[t] = bi;
    __syncthreads();
    for (int d = 512; d > 0; d >>= 1) {
      if (t < d) {
        if (s_rv[t + d] > s_rv[t] ||
            (s_rv[t + d] == s_rv[t] && s_ri[t + d] < s_ri[t])) {
          s_rv[t] = s_rv[t + d]; s_ri[t] = s_ri[t + d];
        }
      }
      __syncthreads();
    }
    if (t == 0) s_chosen[k] = s_ri[0];
    __syncthreads();
  }
  if (t == 0) {
    for (int a = 1; a < 12; ++a) {
      int key = s_chosen[a]; int j = a - 1;
      while (j >= 0 && s_chosen[j] > key) { s_chosen[j + 1] = s_chosen[j]; --j; }
      s_chosen[j + 1] = key;
    }
  }
  __syncthreads();
}

// ---------------- K1: masks + deterministic compaction (ballot scan) --------
__global__ __launch_bounds__(1024) void k_mask(const float* __restrict__ mask_q,
                                               unsigned char* __restrict__ fgm,
                                               unsigned char* __restrict__ bgm,
                                               int* __restrict__ bgsel,
                                               int* __restrict__ cnts) {
  int b = blockIdx.x;
  int t = threadIdx.x;
  int wv = t >> 6, l = t & 63;   // 16 waves
  const float* pred_bg = mask_q + (size_t)b * 2 * NPix;
  const float* pred_fg = pred_bg + NPix;

  __shared__ int   s_wtot[16];
  __shared__ int   s_base[2];
  __shared__ float s_rv[1024];
  __shared__ int   s_ri[1024];
  __shared__ int   s_chosen[12];

  if (t == 0) { s_base[0] = 0; s_base[1] = 0; }
  __syncthreads();

  unsigned long long lmask = (1ull << l) - 1ull;

  for (int chunk = 0; chunk < NPix; chunk += 1024) {
    int n = chunk + t;
    int fgf = 0, bgf = 0;
    if (n < NPix) {
      fgf = pred_fg[n] > 0.5f ? 1 : 0;
      bgf = pred_bg[n] > 0.8f ? 1 : 0;
      fgm[b * NPix + n] = (unsigned char)fgf;
      bgm[b * NPix + n] = (unsigned char)bgf;
    }
    unsigned long long fb = __ballot(fgf != 0);
    unsigned long long bb = __ballot(bgf != 0);
    if (l == 0) s_wtot[wv] = __popcll(fb) | (__popcll(bb) << 16);
    __syncthreads();
    int fsum = 0, bsum = 0, bpre = 0;
#pragma unroll
    for (int w = 0; w < 16; ++w) {
      int v = s_wtot[w];
      if (w < wv) bpre += (v >> 16);
      fsum += v & 0xffff; bsum += (v >> 16);
    }
    if (bgf) {
      int pos = s_base[1] + bpre + (int)__popcll(bb & lmask);
      bgsel[b * NPix + pos] = n;
    }
    __syncthreads();
    if (t == 0) { s_base[0] += fsum; s_base[1] += bsum; }
    __syncthreads();
  }
  int fgcnt = s_base[0];
  int bgcnt = s_base[1];

  if (fgcnt == 0) {
    block_top12(pred_fg, t, s_rv, s_ri, s_chosen);
    if (t < 12) fgm[b * NPix + s_chosen[t]] = 1;
    fgcnt = 12;
    __syncthreads();
  }
  if (bgcnt == 0) {
    block_top12(pred_bg, t, s_rv, s_ri, s_chosen);
    if (t < 12) {
      bgm[b * NPix + s_chosen[t]] = 1;
      bgsel[b * NPix + t] = s_chosen[t];
    }
    bgcnt = 12;
    __syncthreads();
  }
  if (t == 0) { cnts[b] = fgcnt; cnts[4 + b] = bgcnt; }
}

// ---------------- K2 (small-ws fallback only): prototypes -------------------
__global__ __launch_bounds__(256) void k_proto(const float* __restrict__ feature,
                                               const unsigned char* __restrict__ fgm,
                                               const unsigned char* __restrict__ bgm,
                                               const int* __restrict__ cnts,
                                               float* __restrict__ out,
                                               float* __restrict__ bgproto) {
  int c = blockIdx.x, b = blockIdx.y, t = threadIdx.x;
  const float* frow = feature + ((size_t)b * NC + c) * NPix;
  float fs = 0.f, bs = 0.f;
  for (int n = t; n < NPix; n += 256) {
    float v = frow[n];
    fs += v * (float)fgm[b * NPix + n];
    bs += v * (float)bgm[b * NPix + n];
  }
  __shared__ float s1[256], s2[256];
  s1[t] = fs; s2[t] = bs;
  __syncthreads();
  for (int d = 128; d > 0; d >>= 1) {
    if (t < d) { s1[t] += s1[t + d]; s2[t] += s2[t + d]; }
    __syncthreads();
  }
  if (t == 0) {
    out[b * NC + c]     = s1[0] / (float)cnts[b];
    bgproto[b * NC + c] = s2[0] / (float)cnts[4 + b];
  }
}

// ---------------- K3: fused colnorm + fp16 pack + proto (single feature read)
__global__ __launch_bounds__(256) void k_normpack(const float* __restrict__ feature,
                                                  const unsigned char* __restrict__ fgm,
                                                  const unsigned char* __restrict__ bgm,
                                                  float* __restrict__ colnorm,
                                                  unsigned short* __restrict__ Qf,
                                                  float* __restrict__ pp) {
  int b = blockIdx.y, nt = blockIdx.x, t = threadIdx.x;
  int n0 = nt * 64;
  __shared__ float s_sq[16][68];
  __shared__ float s_inv[64];
  __shared__ float s_fg[64], s_bg[64];
  __shared__ unsigned int tl[64][65];
  __shared__ float traw[64][65];
  __shared__ float s_red[2][4][64];
  const float* fb = feature + (size_t)b * NC * NPix;

  // phase A: load into regs + sum of squares
  int p4 = t & 15, cq = t >> 4;
  float4 raw[16];
  float sq0 = 0.f, sq1 = 0.f, sq2 = 0.f, sq3 = 0.f;
  if (n0 + 64 <= NPix) {
#pragma unroll
    for (int j = 0; j < 16; ++j) {
      float4 v = *(const float4*)(fb + (size_t)(cq * 16 + j) * NPix + n0 + p4 * 4);
      raw[j] = v;
      sq0 += v.x * v.x; sq1 += v.y * v.y; sq2 += v.z * v.z; sq3 += v.w * v.w;
    }
  } else {
#pragma unroll
    for (int j = 0; j < 16; ++j) {
      size_t base = (size_t)(cq * 16 + j) * NPix;
      int n = n0 + p4 * 4;
      float4 v;
      v.x = (n + 0 < NPix) ? fb[base + n + 0] : 0.f;
      v.y = (n + 1 < NPix) ? fb[base + n + 1] : 0.f;
      v.z = (n + 2 < NPix) ? fb[base + n + 2] : 0.f;
      v.w = (n + 3 < NPix) ? fb[base + n + 3] : 0.f;
      raw[j] = v;
      sq0 += v.x * v.x; sq1 += v.y * v.y; sq2 += v.z * v.z; sq3 += v.w * v.w;
    }
  }
  s_sq[cq][p4 * 4 + 0] = sq0;
  s_sq[cq][p4 * 4 + 1] = sq1;
  s_sq[cq][p4 * 4 + 2] = sq2;
  s_sq[cq][p4 * 4 + 3] = sq3;
  __syncthreads();
  if (t < 64) {
    float acc = 0.f;
#pragma unroll
    for (int q = 0; q < 16; ++q) acc += s_sq[q][t];
    float nrm = sqrtf(acc);
    int n = n0 + t;
    s_inv[t] = (n < NPix) ? 1.f / nrm : 0.f;
    if (n < NPix) colnorm[b * NPix + n] = nrm;
    s_fg[t] = (n < NPix) ? (float)fgm[b * NPix + n] : 0.f;
    s_bg[t] = (n < NPix) ? (float)bgm[b * NPix + n] : 0.f;
  }
  __syncthreads();

  // phase B: per 64-ch chunk, write traw/tl from registers
  unsigned short* QfB = Qf + (size_t)b * NPix * NC;
  int clbase = (cq & 3) * 16;
  int nlb = p4 * 4;
  float inv0 = s_inv[nlb + 0], inv1 = s_inv[nlb + 1];
  float inv2 = s_inv[nlb + 2], inv3 = s_inv[nlb + 3];
  for (int cs = 0; cs < 4; ++cs) {
    int c0 = cs * 64;
    if ((cq >> 2) == cs) {     // wave cs holds channels [cs*64, cs*64+64)
#pragma unroll
      for (int j = 0; j < 16; ++j) {
        int cl = clbase + j;
        float4 v = raw[j];
        traw[cl][nlb + 0] = v.x;  tl[cl][nlb + 0] = (unsigned int)f2h(v.x * inv0);
        traw[cl][nlb + 1] = v.y;  tl[cl][nlb + 1] = (unsigned int)f2h(v.y * inv1);
        traw[cl][nlb + 2] = v.z;  tl[cl][nlb + 2] = (unsigned int)f2h(v.z * inv2);
        traw[cl][nlb + 3] = v.w;  tl[cl][nlb + 3] = (unsigned int)f2h(v.w * inv3);
      }
    }
    __syncthreads();
    // coalesced fp16 pack (2 ch per u32)
#pragma unroll
    for (int i = 0; i < 8; ++i) {
      int idx = t + 256 * i;
      int n = idx >> 5;
      int cp = idx & 31;
      int row = n0 + n;
      if (row < NPix) {
        unsigned int u = (tl[2 * cp][n] & 0xffffu) | (tl[2 * cp + 1][n] << 16);
        *(unsigned int*)&QfB[(size_t)row * NC + c0 + 2 * cp] = u;
      }
    }
    // proto partials (exact raw values, fixed order)
    {
      int cl = t & 63, pq = t >> 6;
      float pf = 0.f, pb = 0.f;
#pragma unroll
      for (int k = 0; k < 16; ++k) {
        int p = pq * 16 + k;
        float feat = traw[cl][p];
        pf += feat * s_fg[p];
        pb += feat * s_bg[p];
      }
      s_red[0][pq][cl] = pf;
      s_red[1][pq][cl] = pb;
    }
    __syncthreads();
    if (t < 128) {
      int m = t >> 6, cl = t & 63;
      float s = s_red[m][0][cl] + s_red[m][1][cl] + s_red[m][2][cl] + s_red[m][3][cl];
      pp[((size_t)(b * 57 + nt) * 2 + m) * 256 + c0 + cl] = s;
    }
    __syncthreads();
  }
}

// ---------------- K4: merged GEMM1 + V^T build + proto reduce ---------------
// Flattened grid.x per batch: [0,174) GEMM1 (rt=x%29, jt=x/29);
// [174,222) V^T build (u=x-174: jt=u>>2, cs=u&3); x==222 proto reduce.
__global__ __launch_bounds__(256) void k_vg(const unsigned short* __restrict__ Qf,
                                            const float* __restrict__ colnorm,
                                            const int* __restrict__ cnts,
                                            const int* __restrict__ bgsel,
                                            unsigned short* __restrict__ Vg,
                                            const float* __restrict__ pp,
                                            float* __restrict__ out,
                                            float* __restrict__ bgproto,
                                            unsigned short* __restrict__ wbuf,
                                            float* __restrict__ wpart) {
  int b = blockIdx.z;
  int x = blockIdx.x;
  int t = threadIdx.x;

  __shared__ __align__(16) char smem[32768];

  if (x == 222) {                 // ---- proto reduce ----
    int c = t;
    float f = 0.f, g = 0.f;
    for (int nt = 0; nt < 57; ++nt) {
      const float* base = pp + (size_t)(b * 57 + nt) * 2 * 256;
      f += base[c];
      g += base[256 + c];
    }
    out[b * NC + c]     = f / (float)cnts[b];
    bgproto[b * NC + c] = g / (float)cnts[4 + b];
    return;
  }

  int M = cnts[4 + b];
  if (M > MCAP) return;

  if (x >= 174) {                 // ---- V^T fp16 build ----
    int u = x - 174;
    int jt = u >> 2, cs = u & 3;
    int j0 = jt * 64, c0 = cs * 64;
    unsigned short* tl = (unsigned short*)smem;   // [64][73]
    const size_t qoff = (size_t)b * NPix * NC;
#pragma unroll
    for (int i = 0; i < 16; ++i) {
      int idx = t + 256 * i; int j = idx >> 6, ch = idx & 63;
      int jg = j0 + j;
      float v = 0.f;
      if (jg < M) {
        int src = bgsel[b * NPix + jg];
        v = h2f(Qf[qoff + (size_t)src * NC + c0 + ch]) * colnorm[b * NPix + src];
      }
      tl[j * 73 + ch] = f2h(v);
    }
    __syncthreads();
#pragma unroll
    for (int i = 0; i < 16; ++i) {
      int idx = t + 256 * i; int ch = idx >> 6, j = idx & 63;
      Vg[((size_t)b * NC + c0 + ch) * MCAP + j0 + j] = tl[j * 73 + ch];
    }
    return;
  }

  // ---- GEMM1: 128x128 tile, gld_lds + source-side XOR swizzle ----
  int rt = x % 29, jt = x / 29;
  if (jt * 128 >= M) return;
  int wv = t >> 6, l = t & 63;
  int n0 = rt * 128, j0 = jt * 128;

  unsigned short* Ah = (unsigned short*)smem;                // [128][64]
  unsigned short* Bh = (unsigned short*)(smem + 16384);      // [128][64]

  const unsigned short* QfB = Qf + (size_t)b * NPix * NC;

  size_t asrc[4];
  int    aslt[4];
#pragma unroll
  for (int i = 0; i < 4; ++i) {
    int u = i * 256 + wv * 64 + l;           // 0..1023
    int r = u >> 3, sl = u & 7;
    int grow = n0 + r; if (grow > NPix - 1) grow = NPix - 1;
    asrc[i] = (size_t)grow * NC;
    aslt[i] = (sl ^ (r & 7)) << 3;
  }
  size_t bsrc[4];
  int    bslt[4];
#pragma unroll
  for (int i = 0; i < 4; ++i) {
    int u = i * 256 + wv * 64 + l;           // 0..1023
    int r = u >> 3, sl = u & 7;
    int jg = j0 + r;
    int src = (jg < M) ? bgsel[b * NPix + jg] : 0;
    bsrc[i] = (size_t)src * NC;
    bslt[i] = (sl ^ (r & 7)) << 3;
  }

  int lr = l & 15;
  int lk = l >> 4;

  float4v acc[2][8];
#pragma unroll
  for (int rf = 0; rf < 2; ++rf)
#pragma unroll
    for (int cf = 0; cf < 8; ++cf) { float4v z = {0.f,0.f,0.f,0.f}; acc[rf][cf] = z; }

  for (int cc = 0; cc < 4; ++cc) {
    int cbase = cc * 64;
#pragma unroll
    for (int i = 0; i < 4; ++i) {
      int ldso = (i * 256 + wv * 64) * 16;
      gld_lds16(QfB + asrc[i] + cbase + aslt[i], (char*)Ah + ldso);
    }
#pragma unroll
    for (int i = 0; i < 4; ++i) {
      int ldso = (i * 256 + wv * 64) * 16;
      gld_lds16(QfB + bsrc[i] + cbase + bslt[i], (char*)Bh + ldso);
    }
    __syncthreads();   // drains vmcnt -> DMA complete

#pragma unroll
    for (int kk = 0; kk < 2; ++kk) {
      int kslot = kk * 4 + lk;
      half8v ah[2];
#pragma unroll
      for (int rf = 0; rf < 2; ++rf) {
        int r = wv * 32 + rf * 16 + lr;
        int s = (kslot ^ (r & 7)) << 3;
        ah[rf] = *(const half8v*)&Ah[r * 64 + s];
      }
#pragma unroll
      for (int cf = 0; cf < 8; ++cf) {
        int j = cf * 16 + lr;
        int s = (kslot ^ (j & 7)) << 3;
        half8v bh = *(const half8v*)&Bh[j * 64 + s];
#pragma unroll
        for (int rf = 0; rf < 2; ++rf)
          acc[rf][cf] = __builtin_amdgcn_mfma_f32_16x16x32_f16(ah[rf], bh, acc[rf][cf], 0, 0, 0);
      }
    }
    __syncthreads();   // before next-chunk overwrite
  }

  // epilogue: w = exp(2s-2) -> fp16; store + per-row partial sums
  float rs[2][4];
#pragma unroll
  for (int rf = 0; rf < 2; ++rf)
#pragma unroll
    for (int i = 0; i < 4; ++i) rs[rf][i] = 0.f;

#pragma unroll
  for (int rf = 0; rf < 2; ++rf)
#pragma unroll
    for (int cf = 0; cf < 8; ++cf)
#pragma unroll
      for (int i = 0; i < 4; ++i) {
        int row = n0 + wv * 32 + rf * 16 + lk * 4 + i;
        int j = j0 + cf * 16 + lr;
        float s = acc[rf][cf][i];
        unsigned short w16 = (j < M) ? f2h(__expf(2.f * s - 2.f)) : (unsigned short)0;
        if (row < NPix)
          wbuf[((size_t)b * NPix + row) * MCAP + j] = w16;
        rs[rf][i] += h2f(w16);
      }

#pragma unroll
  for (int rf = 0; rf < 2; ++rf)
#pragma unroll
    for (int i = 0; i < 4; ++i) {
      float v = rs[rf][i];
      v += __shfl_xor(v, 1);
      v += __shfl_xor(v, 2);
      v += __shfl_xor(v, 4);
      v += __shfl_xor(v, 8);
      int row = n0 + wv * 32 + rf * 16 + lk * 4 + i;
      if (lr == 0 && row < NPix)
        wpart[((size_t)b * NPix + row) * 12 + jt] = v;
    }
}

// ---------------- K5: GEMM2 fp16 + fused lsum + fused epilogue (standalone) -
__global__ __launch_bounds__(256, 3) void k_gemm2e(const unsigned short* __restrict__ wbuf,
                                                   const unsigned short* __restrict__ Vg,
                                                   const int* __restrict__ cnts,
                                                   const float* __restrict__ wpart,
                                                   const float* __restrict__ bgproto,
                                                   float* __restrict__ out) {
  int b = blockIdx.z; int M = cnts[4 + b]; if (M > MCAP) return;
  int rt = blockIdx.x, cs = blockIdx.y;
  int t = threadIdx.x, wv = t >> 6, l = t & 63;
  int n0 = rt * 128, c0 = cs * 128;
  int arow0 = n0 + wv * 32 + (l & 15);
  int arow1 = arow0 + 16;
  if (arow0 > NPix - 1) arow0 = NPix - 1;
  if (arow1 > NPix - 1) arow1 = NPix - 1;
  const unsigned short* wr0 = wbuf + ((size_t)b * NPix + arow0) * MCAP + (l >> 4) * 8;
  const unsigned short* wr1 = wbuf + ((size_t)b * NPix + arow1) * MCAP + (l >> 4) * 8;
  const unsigned short* vb  = Vg + ((size_t)b * NC + c0 + (l & 15)) * MCAP + (l >> 4) * 8;

  __shared__ float trans[64][129];    // 33 KB: [c_half][n_local]
  __shared__ float s_linv[128];
  __shared__ float s_bp[128];

  float4v acc[2][8];
#pragma unroll
  for (int rf = 0; rf < 2; ++rf)
#pragma unroll
    for (int cf = 0; cf < 8; ++cf) { float4v z = {0.f,0.f,0.f,0.f}; acc[rf][cf] = z; }

  int nkk = (M + 31) >> 5;
  for (int kk = 0; kk < nkk; ++kk) {
    half8v a0 = *(const half8v*)(wr0 + kk * 32);
    half8v a1 = *(const half8v*)(wr1 + kk * 32);
#pragma unroll
    for (int cf = 0; cf < 8; ++cf) {
      half8v bv = *(const half8v*)(vb + (size_t)cf * 16 * MCAP + kk * 32);
      acc[0][cf] = __builtin_amdgcn_mfma_f32_16x16x32_f16(a0, bv, acc[0][cf], 0, 0, 0);
      acc[1][cf] = __builtin_amdgcn_mfma_f32_16x16x32_f16(a1, bv, acc[1][cf], 0, 0, 0);
    }
  }

  // fused lsum: reduce j-tile partials per row (128-wide tiles)
  if (t < 128) {
    int row = n0 + t;
    if (row < NPix) {
      const float* wp = wpart + ((size_t)b * NPix + row) * 12;
      int njt = (M + 127) >> 7;
      float s = 0.f;
      for (int j = 0; j < njt; ++j) s += wp[j];
      s_linv[t] = 1.f / s;
    } else s_linv[t] = 0.f;
    s_bp[t] = bgproto[b * NC + c0 + t];
  }

  int g = l >> 4;
  float* outBP = out + NB * NC;
#pragma unroll
  for (int half = 0; half < 2; ++half) {
    __syncthreads();   // half0: covers s_linv/s_bp; half1: trans reads done
#pragma unroll
    for (int cfl = 0; cfl < 4; ++cfl) {
      int cf = half * 4 + cfl;
#pragma unroll
      for (int rf = 0; rf < 2; ++rf)
#pragma unroll
        for (int i = 0; i < 4; ++i) {
          int c_l = cfl * 16 + (l & 15);
          int n_l = wv * 32 + rf * 16 + g * 4 + i;
          trans[c_l][n_l] = acc[rf][cf][i];
        }
    }
    __syncthreads();
#pragma unroll
    for (int it = 0; it < 8; ++it) {
      int idx = t + 256 * it;       // 0..2047
      int c_l = idx >> 5;           // 0..63
      int q   = idx & 31;           // n-quad
      int n   = n0 + q * 4;
      if (n < NPix) {               // NPix%4==0 -> whole quad in range
        float bpv = s_bp[half * 64 + c_l];
        float4 o;
        o.x = bpv * 0.3f + trans[c_l][q * 4 + 0] * s_linv[q * 4 + 0] * 0.7f;
        o.y = bpv * 0.3f + trans[c_l][q * 4 + 1] * s_linv[q * 4 + 1] * 0.7f;
        o.z = bpv * 0.3f + trans[c_l][q * 4 + 2] * s_linv[q * 4 + 2] * 0.7f;
        o.w = bpv * 0.3f + trans[c_l][q * 4 + 3] * s_linv[q * 4 + 3] * 0.7f;
        *(float4*)&outBP[((size_t)b * NC + c0 + half * 64 + c_l) * NPix + n] = o;
      }
    }
  }
}

// ---------------- fallback: self-normalizing fp32 attention (gated) ---------
__global__ __launch_bounds__(256) void k_attn(const float* __restrict__ feature,
                                              const float* __restrict__ colnorm,
                                              const int* __restrict__ cnts,
                                              const int* __restrict__ bgsel,
                                              const float* __restrict__ bgproto,
                                              float* __restrict__ out,
                                              int gate) {
  int b = blockIdx.y;
  int M = cnts[4 + b];
  if (gate && M <= MCAP) return;
  int tile = blockIdx.x;
  int t = threadIdx.x;
  int rl  = t >> 4;
  int l16 = t & 15;
  int row = tile * 16 + rl;
  const float* feat = feature + (size_t)b * NC * NPix;

  __shared__ float s_k[32][NC];
  __shared__ float s_vn[32];

  float inv_n = 1.f / colnorm[b * NPix + row];
  float q[16];
#pragma unroll
  for (int k = 0; k < 4; ++k)
#pragma unroll
    for (int i = 0; i < 4; ++i) {
      int c = l16 * 4 + 64 * k + i;
      q[k * 4 + i] = feat[(size_t)c * NPix + row] * inv_n;
    }

  float l_acc = 0.f;
  float O[16];
#pragma unroll
  for (int i = 0; i < 16; ++i) O[i] = 0.f;

  for (int kt = 0; kt < M; kt += 32) {
    int jmax = min(32, M - kt);
    __syncthreads();
    for (int u = t; u < 32 * 64; u += 256) {
      int jj = u >> 6;
      int cc = (u & 63) << 2;
      if (jj < jmax) {
        int src = bgsel[b * NPix + kt + jj];
        float inv = 1.f / colnorm[b * NPix + src];
        float4 v;
        v.x = feat[(size_t)(cc + 0) * NPix + src] * inv;
        v.y = feat[(size_t)(cc + 1) * NPix + src] * inv;
        v.z = feat[(size_t)(cc + 2) * NPix + src] * inv;
        v.w = feat[(size_t)(cc + 3) * NPix + src] * inv;
        *(float4*)&s_k[jj][cc] = v;
      }
    }
    if (t < 32)
      s_vn[t] = (t < jmax) ? colnorm[b * NPix + bgsel[b * NPix + kt + t]] : 0.f;
    __syncthreads();

    for (int j = 0; j < jmax; ++j) {
      float kv[16];
      float s = 0.f;
#pragma unroll
      for (int k = 0; k < 4; ++k) {
        float4 v4 = *(const float4*)&s_k[j][l16 * 4 + 64 * k];
        kv[k * 4 + 0] = v4.x; kv[k * 4 + 1] = v4.y;
        kv[k * 4 + 2] = v4.z; kv[k * 4 + 3] = v4.w;
        s += q[k * 4 + 0] * v4.x + q[k * 4 + 1] * v4.y +
             q[k * 4 + 2] * v4.z + q[k * 4 + 3] * v4.w;
      }
      s += __shfl_xor(s, 1);
      s += __shfl_xor(s, 2);
      s += __shfl_xor(s, 4);
      s += __shfl_xor(s, 8);
      float e = __expf(2.f * s - 2.f);
      l_acc += e;
      float ev = e * s_vn[j];
#pragma unroll
      for (int i = 0; i < 16; ++i) O[i] += ev * kv[i];
    }
  }

  float inv_l = 1.f / l_acc;
  float* outBP = out + NB * NC;
  const float* bp = bgproto + b * NC;
#pragma unroll
  for (int k = 0; k < 4; ++k)
#pragma unroll
    for (int i = 0; i < 4; ++i) {
      int c = l16 * 4 + 64 * k + i;
      outBP[((size_t)b * NC + c) * NPix + row] =
          bp[c] * 0.3f + O[k * 4 + i] * inv_l * 0.7f;
    }
}

// ---------------------------------------------------------------------------
extern "C" void kernel_launch(void* const* d_in, const int* in_sizes, int n_in,
                              void* d_out, int out_size, void* d_ws, size_t ws_size,
                              hipStream_t stream) {
  const float* feature = (const float*)d_in[0];
  const float* mask_q  = (const float*)d_in[1];
  float* out = (float*)d_out;
  char* ws = (char*)d_ws;

  const size_t BIG_NEED = 32428160ULL;
  if (ws_size >= BIG_NEED) {
    // big-mode carve (all offsets 16B-aligned, sizes in BYTES):
    float* colnorm   = (float*)(ws + 0);          //    57,600
    float* bgproto   = (float*)(ws + 115200);     //     4,096
    int*   cnts      = (int*)  (ws + 119296);     //       256 slot
    int*   bgsel     = (int*)  (ws + 119552);     //    57,600 -> 177,152
    unsigned char* fgm = (unsigned char*)(ws + 177152);    // 14,400
    unsigned char* bgm = (unsigned char*)(ws + 191552);    // 14,400 -> 205,952
    float* pp        = (float*)(ws + 205952);     //   466,944 -> 672,896
    unsigned short* Vg  = (unsigned short*)(ws + 672896);   //  1,572,864 -> 2,245,760
    unsigned short* Qf  = (unsigned short*)(ws + 2245760);  //  7,372,800 -> 9,618,560
    unsigned short* wbuf = (unsigned short*)(ws + 9618560); // 22,118,400 -> 31,736,960
    float* wpart     = (float*)(ws + 31736960);   //   691,200 -> 32,428,160

    k_mask    <<<NB,               1024, 0, stream>>>(mask_q, fgm, bgm, bgsel, cnts);
    k_normpack<<<dim3(57, NB),     256, 0, stream>>>(feature, fgm, bgm, colnorm, Qf, pp);
    k_vg      <<<dim3(223, 1, NB), 256, 0, stream>>>(Qf, colnorm, cnts, bgsel, Vg,
                                                     pp, out, bgproto, wbuf, wpart);
    k_gemm2e  <<<dim3(29, 2, NB),  256, 0, stream>>>(wbuf, Vg, cnts, wpart, bgproto, out);
    // fallback path, active only for batches with M > MCAP
    k_attn    <<<dim3(225, NB),    256, 0, stream>>>(feature, colnorm, cnts, bgsel,
                                                     bgproto, out, 1);
  } else {
    // small-ws fallback: simple kernels, self-normalizing attention
    float* colnorm  = (float*)(ws + 0);
    float* bgproto  = (float*)(ws + 115200);
    int*   cnts     = (int*)  (ws + 119296);
    int*   bgsel    = (int*)  (ws + 119552);
    unsigned char* fgm = (unsigned char*)(ws + 177152);
    unsigned char* bgm = (unsigned char*)(ws + 191552);

    k_colnorm<<<dim3(15, NB), 256, 0, stream>>>(feature, colnorm);
    k_mask   <<<NB,           1024, 0, stream>>>(mask_q, fgm, bgm, bgsel, cnts);
    k_proto  <<<dim3(NC, NB), 256, 0, stream>>>(feature, fgm, bgm, cnts, out, bgproto);
    k_attn   <<<dim3(225, NB),256, 0, stream>>>(feature, colnorm, cnts, bgsel,
                                                bgproto, out, 0);
  }
}

// Round 13
// 79.821 us; speedup vs baseline: 1.5914x; 1.0264x over previous
//
#include <hip/hip_runtime.h>
#include <math.h>
#include <float.h>

#define NPix 3600
#define NC   256
#define NB   4
#define MCAP 768

typedef __attribute__((ext_vector_type(8))) _Float16 half8v;
typedef __attribute__((ext_vector_type(4))) float float4v;

__device__ __forceinline__ unsigned short f2h(float x) {
  _Float16 h = (_Float16)x;           // RTNE
  unsigned short u; __builtin_memcpy(&u, &h, 2); return u;
}
__device__ __forceinline__ float h2f(unsigned short u) {
  _Float16 h; __builtin_memcpy(&h, &u, 2); return (float)h;
}

// async global->LDS DMA, 16B per lane; LDS dest must be wave-uniform base
__device__ __forceinline__ void gld_lds16(const void* g, void* l) {
  __builtin_amdgcn_global_load_lds(
      (const __attribute__((address_space(1))) unsigned int*)g,
      (__attribute__((address_space(3))) unsigned int*)l, 16, 0, 0);
}

// ---------------- K0 (small-ws fallback only): column L2 norms --------------
__global__ __launch_bounds__(256) void k_colnorm(const float* __restrict__ feature,
                                                 float* __restrict__ colnorm) {
  int b = blockIdx.y;
  int n = blockIdx.x * 256 + threadIdx.x;
  if (n >= NPix) return;
  const float* feat = feature + (size_t)b * NC * NPix;
  float acc = 0.f;
#pragma unroll 8
  for (int c = 0; c < NC; ++c) {
    float v = feat[(size_t)c * NPix + n];
    acc += v * v;
  }
  colnorm[b * NPix + n] = sqrtf(acc);
}

// ---------------- top-12 fallback (block-wide iterative argmax, 1024 thr) ---
__device__ void block_top12(const float* __restrict__ p, int t,
                            float* s_rv, int* s_ri, int* s_chosen) {
  for (int k = 0; k < 12; ++k) {
    float best = -FLT_MAX;
    int bi = 0x7fffffff;
    for (int n = t; n < NPix; n += 1024) {
      bool excl = false;
      for (int j = 0; j < k; ++j)
        if (s_chosen[j] == n) excl = true;
      if (!excl) {
        float v = p[n];
        if (v > best || (v == best && n < bi)) { best = v; bi = n; }
      }
    }
    s_rv[t] = best; s_ri[t] = bi;
    __syncthreads();
    for (int d = 512; d > 0; d >>= 1) {
      if (t < d) {
        if (s_rv[t + d] > s_rv[t] ||
            (s_rv[t + d] == s_rv[t] && s_ri[t + d] < s_ri[t])) {
          s_rv[t] = s_rv[t + d]; s_ri[t] = s_ri[t + d];
        }
      }
      __syncthreads();
    }
    if (t == 0) s_chosen[k] = s_ri[0];
    __syncthreads();
  }
  if (t == 0) {
    for (int a = 1; a < 12; ++a) {
      int key = s_chosen[a]; int j = a - 1;
      while (j >= 0 && s_chosen[j] > key) { s_chosen[j + 1] = s_chosen[j]; --j; }
      s_chosen[j + 1] = key;
    }
  }
  __syncthreads();
}

// ---------------- K1: masks + deterministic compaction (ballot scan) --------
__global__ __launch_bounds__(1024) void k_mask(const float* __restrict__ mask_q,
                                               unsigned char* __restrict__ fgm,
                                               unsigned char* __restrict__ bgm,
                                               int* __restrict__ bgsel,
                                               int* __restrict__ cnts) {
  int b = blockIdx.x;
  int t = threadIdx.x;
  int wv = t >> 6, l = t & 63;   // 16 waves
  const float* pred_bg = mask_q + (size_t)b * 2 * NPix;
  const float* pred_fg = pred_bg + NPix;

  __shared__ int   s_wtot[16];
  __shared__ int   s_base[2];
  __shared__ float s_rv[1024];
  __shared__ int   s_ri[1024];
  __shared__ int   s_chosen[12];

  if (t == 0) { s_base[0] = 0; s_base[1] = 0; }
  __syncthreads();

  unsigned long long lmask = (1ull << l) - 1ull;

  for (int chunk = 0; chunk < NPix; chunk += 1024) {
    int n = chunk + t;
    int fgf = 0, bgf = 0;
    if (n < NPix) {
      fgf = pred_fg[n] > 0.5f ? 1 : 0;
      bgf = pred_bg[n] > 0.8f ? 1 : 0;
      fgm[b * NPix + n] = (unsigned char)fgf;
      bgm[b * NPix + n] = (unsigned char)bgf;
    }
    unsigned long long fb = __ballot(fgf != 0);
    unsigned long long bb = __ballot(bgf != 0);
    if (l == 0) s_wtot[wv] = __popcll(fb) | (__popcll(bb) << 16);
    __syncthreads();
    int fsum = 0, bsum = 0, bpre = 0;
#pragma unroll
    for (int w = 0; w < 16; ++w) {
      int v = s_wtot[w];
      if (w < wv) bpre += (v >> 16);
      fsum += v & 0xffff; bsum += (v >> 16);
    }
    if (bgf) {
      int pos = s_base[1] + bpre + (int)__popcll(bb & lmask);
      bgsel[b * NPix + pos] = n;
    }
    __syncthreads();
    if (t == 0) { s_base[0] += fsum; s_base[1] += bsum; }
    __syncthreads();
  }
  int fgcnt = s_base[0];
  int bgcnt = s_base[1];

  if (fgcnt == 0) {
    block_top12(pred_fg, t, s_rv, s_ri, s_chosen);
    if (t < 12) fgm[b * NPix + s_chosen[t]] = 1;
    fgcnt = 12;
    __syncthreads();
  }
  if (bgcnt == 0) {
    block_top12(pred_bg, t, s_rv, s_ri, s_chosen);
    if (t < 12) {
      bgm[b * NPix + s_chosen[t]] = 1;
      bgsel[b * NPix + t] = s_chosen[t];
    }
    bgcnt = 12;
    __syncthreads();
  }
  if (t == 0) { cnts[b] = fgcnt; cnts[4 + b] = bgcnt; }
}

// ---------------- K2 (small-ws fallback only): prototypes -------------------
__global__ __launch_bounds__(256) void k_proto(const float* __restrict__ feature,
                                               const unsigned char* __restrict__ fgm,
                                               const unsigned char* __restrict__ bgm,
                                               const int* __restrict__ cnts,
                                               float* __restrict__ out,
                                               float* __restrict__ bgproto) {
  int c = blockIdx.x, b = blockIdx.y, t = threadIdx.x;
  const float* frow = feature + ((size_t)b * NC + c) * NPix;
  float fs = 0.f, bs = 0.f;
  for (int n = t; n < NPix; n += 256) {
    float v = frow[n];
    fs += v * (float)fgm[b * NPix + n];
    bs += v * (float)bgm[b * NPix + n];
  }
  __shared__ float s1[256], s2[256];
  s1[t] = fs; s2[t] = bs;
  __syncthreads();
  for (int d = 128; d > 0; d >>= 1) {
    if (t < d) { s1[t] += s1[t + d]; s2[t] += s2[t + d]; }
    __syncthreads();
  }
  if (t == 0) {
    out[b * NC + c]     = s1[0] / (float)cnts[b];
    bgproto[b * NC + c] = s2[0] / (float)cnts[4 + b];
  }
}

// ---------------- K3: colnorm + fp16 pack + proto, all from registers -------
// Phase A: load 64px x 256ch working set into regs + sum-of-squares.
// Phase B: Qf written straight from regs (32B contiguous per row per thread);
// proto partials via 16-lane shfl_xor butterfly (no traw/tl LDS, 2 barriers).
__global__ __launch_bounds__(256) void k_normpack(const float* __restrict__ feature,
                                                  const unsigned char* __restrict__ fgm,
                                                  const unsigned char* __restrict__ bgm,
                                                  float* __restrict__ colnorm,
                                                  unsigned short* __restrict__ Qf,
                                                  float* __restrict__ pp) {
  int b = blockIdx.y, nt = blockIdx.x, t = threadIdx.x;
  int n0 = nt * 64;
  __shared__ float s_sq[16][68];
  __shared__ float s_inv[64];
  __shared__ float s_fg[64], s_bg[64];
  const float* fb = feature + (size_t)b * NC * NPix;

  // phase A: load into regs + sum of squares
  int p4 = t & 15, cq = t >> 4;
  float4 raw[16];
  float sq0 = 0.f, sq1 = 0.f, sq2 = 0.f, sq3 = 0.f;
  if (n0 + 64 <= NPix) {
#pragma unroll
    for (int j = 0; j < 16; ++j) {
      float4 v = *(const float4*)(fb + (size_t)(cq * 16 + j) * NPix + n0 + p4 * 4);
      raw[j] = v;
      sq0 += v.x * v.x; sq1 += v.y * v.y; sq2 += v.z * v.z; sq3 += v.w * v.w;
    }
  } else {
#pragma unroll
    for (int j = 0; j < 16; ++j) {
      size_t base = (size_t)(cq * 16 + j) * NPix;
      int n = n0 + p4 * 4;
      float4 v;
      v.x = (n + 0 < NPix) ? fb[base + n + 0] : 0.f;
      v.y = (n + 1 < NPix) ? fb[base + n + 1] : 0.f;
      v.z = (n + 2 < NPix) ? fb[base + n + 2] : 0.f;
      v.w = (n + 3 < NPix) ? fb[base + n + 3] : 0.f;
      raw[j] = v;
      sq0 += v.x * v.x; sq1 += v.y * v.y; sq2 += v.z * v.z; sq3 += v.w * v.w;
    }
  }
  s_sq[cq][p4 * 4 + 0] = sq0;
  s_sq[cq][p4 * 4 + 1] = sq1;
  s_sq[cq][p4 * 4 + 2] = sq2;
  s_sq[cq][p4 * 4 + 3] = sq3;
  __syncthreads();
  if (t < 64) {
    float acc = 0.f;
#pragma unroll
    for (int q = 0; q < 16; ++q) acc += s_sq[q][t];
    float nrm = sqrtf(acc);
    int n = n0 + t;
    s_inv[t] = (n < NPix) ? 1.f / nrm : 0.f;
    if (n < NPix) colnorm[b * NPix + n] = nrm;
    s_fg[t] = (n < NPix) ? (float)fgm[b * NPix + n] : 0.f;
    s_bg[t] = (n < NPix) ? (float)bgm[b * NPix + n] : 0.f;
  }
  __syncthreads();

  float inv0 = s_inv[p4 * 4 + 0], inv1 = s_inv[p4 * 4 + 1];
  float inv2 = s_inv[p4 * 4 + 2], inv3 = s_inv[p4 * 4 + 3];
  float fg0 = s_fg[p4 * 4 + 0], fg1 = s_fg[p4 * 4 + 1];
  float fg2 = s_fg[p4 * 4 + 2], fg3 = s_fg[p4 * 4 + 3];
  float bg0 = s_bg[p4 * 4 + 0], bg1 = s_bg[p4 * 4 + 1];
  float bg2 = s_bg[p4 * 4 + 2], bg3 = s_bg[p4 * 4 + 3];

  // phase B1: Qf straight from registers (per row: 32B contiguous per thread)
  unsigned short* QfB = Qf + (size_t)b * NPix * NC;
#pragma unroll
  for (int i = 0; i < 4; ++i) {
    int row = n0 + p4 * 4 + i;
    if (row < NPix) {
      float invi = (i == 0) ? inv0 : (i == 1) ? inv1 : (i == 2) ? inv2 : inv3;
      unsigned int ub[8];
#pragma unroll
      for (int jp = 0; jp < 8; ++jp) {
        float4 ve = raw[2 * jp + 0];
        float4 vo = raw[2 * jp + 1];
        float fe = (i == 0) ? ve.x : (i == 1) ? ve.y : (i == 2) ? ve.z : ve.w;
        float fo = (i == 0) ? vo.x : (i == 1) ? vo.y : (i == 2) ? vo.z : vo.w;
        ub[jp] = (unsigned int)f2h(fe * invi) | ((unsigned int)f2h(fo * invi) << 16);
      }
      unsigned int* dst = (unsigned int*)&QfB[(size_t)row * NC + cq * 16];
      *(uint4*)(dst + 0) = make_uint4(ub[0], ub[1], ub[2], ub[3]);
      *(uint4*)(dst + 4) = make_uint4(ub[4], ub[5], ub[6], ub[7]);
    }
  }

  // phase B2: proto partials via 16-lane butterfly (lanes sharing cq are
  // consecutive; xor 1/2/4/8 stays in-group)
  float pf[16], pb[16];
#pragma unroll
  for (int j = 0; j < 16; ++j) {
    float4 v = raw[j];
    pf[j] = v.x * fg0 + v.y * fg1 + v.z * fg2 + v.w * fg3;
    pb[j] = v.x * bg0 + v.y * bg1 + v.z * bg2 + v.w * bg3;
  }
#pragma unroll
  for (int j = 0; j < 16; ++j) {
#pragma unroll
    for (int d = 1; d < 16; d <<= 1) {
      pf[j] += __shfl_xor(pf[j], d);
      pb[j] += __shfl_xor(pb[j], d);
    }
  }
  if (p4 == 0) {
    float* ppb = pp + (size_t)(b * 57 + nt) * 2 * 256;
#pragma unroll
    for (int j = 0; j < 16; ++j) {
      ppb[cq * 16 + j]       = pf[j];
      ppb[256 + cq * 16 + j] = pb[j];
    }
  }
}

// ---------------- K4: merged GEMM1 + V^T build + proto reduce ---------------
// Flattened grid.x per batch: [0,174) GEMM1 (rt=x%29, jt=x/29);
// [174,222) V^T build (u=x-174: jt=u>>2, cs=u&3); x==222 proto reduce.
__global__ __launch_bounds__(256) void k_vg(const unsigned short* __restrict__ Qf,
                                            const float* __restrict__ colnorm,
                                            const int* __restrict__ cnts,
                                            const int* __restrict__ bgsel,
                                            unsigned short* __restrict__ Vg,
                                            const float* __restrict__ pp,
                                            float* __restrict__ out,
                                            float* __restrict__ bgproto,
                                            unsigned short* __restrict__ wbuf,
                                            float* __restrict__ wpart) {
  int b = blockIdx.z;
  int x = blockIdx.x;
  int t = threadIdx.x;

  __shared__ __align__(16) char smem[32768];

  if (x == 222) {                 // ---- proto reduce ----
    int c = t;
    float f = 0.f, g = 0.f;
    for (int nt = 0; nt < 57; ++nt) {
      const float* base = pp + (size_t)(b * 57 + nt) * 2 * 256;
      f += base[c];
      g += base[256 + c];
    }
    out[b * NC + c]     = f / (float)cnts[b];
    bgproto[b * NC + c] = g / (float)cnts[4 + b];
    return;
  }

  int M = cnts[4 + b];
  if (M > MCAP) return;

  if (x >= 174) {                 // ---- V^T fp16 build ----
    int u = x - 174;
    int jt = u >> 2, cs = u & 3;
    int j0 = jt * 64, c0 = cs * 64;
    unsigned short* tl = (unsigned short*)smem;   // [64][73]
    const size_t qoff = (size_t)b * NPix * NC;
#pragma unroll
    for (int i = 0; i < 16; ++i) {
      int idx = t + 256 * i; int j = idx >> 6, ch = idx & 63;
      int jg = j0 + j;
      float v = 0.f;
      if (jg < M) {
        int src = bgsel[b * NPix + jg];
        v = h2f(Qf[qoff + (size_t)src * NC + c0 + ch]) * colnorm[b * NPix + src];
      }
      tl[j * 73 + ch] = f2h(v);
    }
    __syncthreads();
#pragma unroll
    for (int i = 0; i < 16; ++i) {
      int idx = t + 256 * i; int ch = idx >> 6, j = idx & 63;
      Vg[((size_t)b * NC + c0 + ch) * MCAP + j0 + j] = tl[j * 73 + ch];
    }
    return;
  }

  // ---- GEMM1: 128x128 tile, gld_lds + source-side XOR swizzle ----
  int rt = x % 29, jt = x / 29;
  if (jt * 128 >= M) return;
  int wv = t >> 6, l = t & 63;
  int n0 = rt * 128, j0 = jt * 128;

  unsigned short* Ah = (unsigned short*)smem;                // [128][64]
  unsigned short* Bh = (unsigned short*)(smem + 16384);      // [128][64]

  const unsigned short* QfB = Qf + (size_t)b * NPix * NC;

  size_t asrc[4];
  int    aslt[4];
#pragma unroll
  for (int i = 0; i < 4; ++i) {
    int u = i * 256 + wv * 64 + l;           // 0..1023
    int r = u >> 3, sl = u & 7;
    int grow = n0 + r; if (grow > NPix - 1) grow = NPix - 1;
    asrc[i] = (size_t)grow * NC;
    aslt[i] = (sl ^ (r & 7)) << 3;
  }
  size_t bsrc[4];
  int    bslt[4];
#pragma unroll
  for (int i = 0; i < 4; ++i) {
    int u = i * 256 + wv * 64 + l;           // 0..1023
    int r = u >> 3, sl = u & 7;
    int jg = j0 + r;
    int src = (jg < M) ? bgsel[b * NPix + jg] : 0;
    bsrc[i] = (size_t)src * NC;
    bslt[i] = (sl ^ (r & 7)) << 3;
  }

  int lr = l & 15;
  int lk = l >> 4;

  float4v acc[2][8];
#pragma unroll
  for (int rf = 0; rf < 2; ++rf)
#pragma unroll
    for (int cf = 0; cf < 8; ++cf) { float4v z = {0.f,0.f,0.f,0.f}; acc[rf][cf] = z; }

  for (int cc = 0; cc < 4; ++cc) {
    int cbase = cc * 64;
#pragma unroll
    for (int i = 0; i < 4; ++i) {
      int ldso = (i * 256 + wv * 64) * 16;
      gld_lds16(QfB + asrc[i] + cbase + aslt[i], (char*)Ah + ldso);
    }
#pragma unroll
    for (int i = 0; i < 4; ++i) {
      int ldso = (i * 256 + wv * 64) * 16;
      gld_lds16(QfB + bsrc[i] + cbase + bslt[i], (char*)Bh + ldso);
    }
    __syncthreads();   // drains vmcnt -> DMA complete

#pragma unroll
    for (int kk = 0; kk < 2; ++kk) {
      int kslot = kk * 4 + lk;
      half8v ah[2];
#pragma unroll
      for (int rf = 0; rf < 2; ++rf) {
        int r = wv * 32 + rf * 16 + lr;
        int s = (kslot ^ (r & 7)) << 3;
        ah[rf] = *(const half8v*)&Ah[r * 64 + s];
      }
#pragma unroll
      for (int cf = 0; cf < 8; ++cf) {
        int j = cf * 16 + lr;
        int s = (kslot ^ (j & 7)) << 3;
        half8v bh = *(const half8v*)&Bh[j * 64 + s];
#pragma unroll
        for (int rf = 0; rf < 2; ++rf)
          acc[rf][cf] = __builtin_amdgcn_mfma_f32_16x16x32_f16(ah[rf], bh, acc[rf][cf], 0, 0, 0);
      }
    }
    __syncthreads();   // before next-chunk overwrite
  }

  // epilogue: w = exp(2s-2) -> fp16; store + per-row partial sums
  float rs[2][4];
#pragma unroll
  for (int rf = 0; rf < 2; ++rf)
#pragma unroll
    for (int i = 0; i < 4; ++i) rs[rf][i] = 0.f;

#pragma unroll
  for (int rf = 0; rf < 2; ++rf)
#pragma unroll
    for (int cf = 0; cf < 8; ++cf)
#pragma unroll
      for (int i = 0; i < 4; ++i) {
        int row = n0 + wv * 32 + rf * 16 + lk * 4 + i;
        int j = j0 + cf * 16 + lr;
        float s = acc[rf][cf][i];
        unsigned short w16 = (j < M) ? f2h(__expf(2.f * s - 2.f)) : (unsigned short)0;
        if (row < NPix)
          wbuf[((size_t)b * NPix + row) * MCAP + j] = w16;
        rs[rf][i] += h2f(w16);
      }

#pragma unroll
  for (int rf = 0; rf < 2; ++rf)
#pragma unroll
    for (int i = 0; i < 4; ++i) {
      float v = rs[rf][i];
      v += __shfl_xor(v, 1);
      v += __shfl_xor(v, 2);
      v += __shfl_xor(v, 4);
      v += __shfl_xor(v, 8);
      int row = n0 + wv * 32 + rf * 16 + lk * 4 + i;
      if (lr == 0 && row < NPix)
        wpart[((size_t)b * NPix + row) * 12 + jt] = v;
    }
}

// ---------------- K5: GEMM2 fp16 + fused lsum + fused epilogue (standalone) -
__global__ __launch_bounds__(256, 3) void k_gemm2e(const unsigned short* __restrict__ wbuf,
                                                   const unsigned short* __restrict__ Vg,
                                                   const int* __restrict__ cnts,
                                                   const float* __restrict__ wpart,
                                                   const float* __restrict__ bgproto,
                                                   float* __restrict__ out) {
  int b = blockIdx.z; int M = cnts[4 + b]; if (M > MCAP) return;
  int rt = blockIdx.x, cs = blockIdx.y;
  int t = threadIdx.x, wv = t >> 6, l = t & 63;
  int n0 = rt * 128, c0 = cs * 128;
  int arow0 = n0 + wv * 32 + (l & 15);
  int arow1 = arow0 + 16;
  if (arow0 > NPix - 1) arow0 = NPix - 1;
  if (arow1 > NPix - 1) arow1 = NPix - 1;
  const unsigned short* wr0 = wbuf + ((size_t)b * NPix + arow0) * MCAP + (l >> 4) * 8;
  const unsigned short* wr1 = wbuf + ((size_t)b * NPix + arow1) * MCAP + (l >> 4) * 8;
  const unsigned short* vb  = Vg + ((size_t)b * NC + c0 + (l & 15)) * MCAP + (l >> 4) * 8;

  __shared__ float trans[64][129];    // 33 KB: [c_half][n_local]
  __shared__ float s_linv[128];
  __shared__ float s_bp[128];

  float4v acc[2][8];
#pragma unroll
  for (int rf = 0; rf < 2; ++rf)
#pragma unroll
    for (int cf = 0; cf < 8; ++cf) { float4v z = {0.f,0.f,0.f,0.f}; acc[rf][cf] = z; }

  int nkk = (M + 31) >> 5;
  for (int kk = 0; kk < nkk; ++kk) {
    half8v a0 = *(const half8v*)(wr0 + kk * 32);
    half8v a1 = *(const half8v*)(wr1 + kk * 32);
#pragma unroll
    for (int cf = 0; cf < 8; ++cf) {
      half8v bv = *(const half8v*)(vb + (size_t)cf * 16 * MCAP + kk * 32);
      acc[0][cf] = __builtin_amdgcn_mfma_f32_16x16x32_f16(a0, bv, acc[0][cf], 0, 0, 0);
      acc[1][cf] = __builtin_amdgcn_mfma_f32_16x16x32_f16(a1, bv, acc[1][cf], 0, 0, 0);
    }
  }

  // fused lsum: reduce j-tile partials per row (128-wide tiles)
  if (t < 128) {
    int row = n0 + t;
    if (row < NPix) {
      const float* wp = wpart + ((size_t)b * NPix + row) * 12;
      int njt = (M + 127) >> 7;
      float s = 0.f;
      for (int j = 0; j < njt; ++j) s += wp[j];
      s_linv[t] = 1.f / s;
    } else s_linv[t] = 0.f;
    s_bp[t] = bgproto[b * NC + c0 + t];
  }

  int g = l >> 4;
  float* outBP = out + NB * NC;
#pragma unroll
  for (int half = 0; half < 2; ++half) {
    __syncthreads();   // half0: covers s_linv/s_bp; half1: trans reads done
#pragma unroll
    for (int cfl = 0; cfl < 4; ++cfl) {
      int cf = half * 4 + cfl;
#pragma unroll
      for (int rf = 0; rf < 2; ++rf)
#pragma unroll
        for (int i = 0; i < 4; ++i) {
          int c_l = cfl * 16 + (l & 15);
          int n_l = wv * 32 + rf * 16 + g * 4 + i;
          trans[c_l][n_l] = acc[rf][cf][i];
        }
    }
    __syncthreads();
#pragma unroll
    for (int it = 0; it < 8; ++it) {
      int idx = t + 256 * it;       // 0..2047
      int c_l = idx >> 5;           // 0..63
      int q   = idx & 31;           // n-quad
      int n   = n0 + q * 4;
      if (n < NPix) {               // NPix%4==0 -> whole quad in range
        float bpv = s_bp[half * 64 + c_l];
        float4 o;
        o.x = bpv * 0.3f + trans[c_l][q * 4 + 0] * s_linv[q * 4 + 0] * 0.7f;
        o.y = bpv * 0.3f + trans[c_l][q * 4 + 1] * s_linv[q * 4 + 1] * 0.7f;
        o.z = bpv * 0.3f + trans[c_l][q * 4 + 2] * s_linv[q * 4 + 2] * 0.7f;
        o.w = bpv * 0.3f + trans[c_l][q * 4 + 3] * s_linv[q * 4 + 3] * 0.7f;
        *(float4*)&outBP[((size_t)b * NC + c0 + half * 64 + c_l) * NPix + n] = o;
      }
    }
  }
}

// ---------------- fallback: self-normalizing fp32 attention (gated) ---------
__global__ __launch_bounds__(256) void k_attn(const float* __restrict__ feature,
                                              const float* __restrict__ colnorm,
                                              const int* __restrict__ cnts,
                                              const int* __restrict__ bgsel,
                                              const float* __restrict__ bgproto,
                                              float* __restrict__ out,
                                              int gate) {
  int b = blockIdx.y;
  int M = cnts[4 + b];
  if (gate && M <= MCAP) return;
  int tile = blockIdx.x;
  int t = threadIdx.x;
  int rl  = t >> 4;
  int l16 = t & 15;
  int row = tile * 16 + rl;
  const float* feat = feature + (size_t)b * NC * NPix;

  __shared__ float s_k[32][NC];
  __shared__ float s_vn[32];

  float inv_n = 1.f / colnorm[b * NPix + row];
  float q[16];
#pragma unroll
  for (int k = 0; k < 4; ++k)
#pragma unroll
    for (int i = 0; i < 4; ++i) {
      int c = l16 * 4 + 64 * k + i;
      q[k * 4 + i] = feat[(size_t)c * NPix + row] * inv_n;
    }

  float l_acc = 0.f;
  float O[16];
#pragma unroll
  for (int i = 0; i < 16; ++i) O[i] = 0.f;

  for (int kt = 0; kt < M; kt += 32) {
    int jmax = min(32, M - kt);
    __syncthreads();
    for (int u = t; u < 32 * 64; u += 256) {
      int jj = u >> 6;
      int cc = (u & 63) << 2;
      if (jj < jmax) {
        int src = bgsel[b * NPix + kt + jj];
        float inv = 1.f / colnorm[b * NPix + src];
        float4 v;
        v.x = feat[(size_t)(cc + 0) * NPix + src] * inv;
        v.y = feat[(size_t)(cc + 1) * NPix + src] * inv;
        v.z = feat[(size_t)(cc + 2) * NPix + src] * inv;
        v.w = feat[(size_t)(cc + 3) * NPix + src] * inv;
        *(float4*)&s_k[jj][cc] = v;
      }
    }
    if (t < 32)
      s_vn[t] = (t < jmax) ? colnorm[b * NPix + bgsel[b * NPix + kt + t]] : 0.f;
    __syncthreads();

    for (int j = 0; j < jmax; ++j) {
      float kv[16];
      float s = 0.f;
#pragma unroll
      for (int k = 0; k < 4; ++k) {
        float4 v4 = *(const float4*)&s_k[j][l16 * 4 + 64 * k];
        kv[k * 4 + 0] = v4.x; kv[k * 4 + 1] = v4.y;
        kv[k * 4 + 2] = v4.z; kv[k * 4 + 3] = v4.w;
        s += q[k * 4 + 0] * v4.x + q[k * 4 + 1] * v4.y +
             q[k * 4 + 2] * v4.z + q[k * 4 + 3] * v4.w;
      }
      s += __shfl_xor(s, 1);
      s += __shfl_xor(s, 2);
      s += __shfl_xor(s, 4);
      s += __shfl_xor(s, 8);
      float e = __expf(2.f * s - 2.f);
      l_acc += e;
      float ev = e * s_vn[j];
#pragma unroll
      for (int i = 0; i < 16; ++i) O[i] += ev * kv[i];
    }
  }

  float inv_l = 1.f / l_acc;
  float* outBP = out + NB * NC;
  const float* bp = bgproto + b * NC;
#pragma unroll
  for (int k = 0; k < 4; ++k)
#pragma unroll
    for (int i = 0; i < 4; ++i) {
      int c = l16 * 4 + 64 * k + i;
      outBP[((size_t)b * NC + c) * NPix + row] =
          bp[c] * 0.3f + O[k * 4 + i] * inv_l * 0.7f;
    }
}

// ---------------------------------------------------------------------------
extern "C" void kernel_launch(void* const* d_in, const int* in_sizes, int n_in,
                              void* d_out, int out_size, void* d_ws, size_t ws_size,
                              hipStream_t stream) {
  const float* feature = (const float*)d_in[0];
  const float* mask_q  = (const float*)d_in[1];
  float* out = (float*)d_out;
  char* ws = (char*)d_ws;

  const size_t BIG_NEED = 32428160ULL;
  if (ws_size >= BIG_NEED) {
    // big-mode carve (all offsets 16B-aligned, sizes in BYTES):
    float* colnorm   = (float*)(ws + 0);          //    57,600
    float* bgproto   = (float*)(ws + 115200);     //     4,096
    int*   cnts      = (int*)  (ws + 119296);     //       256 slot
    int*   bgsel     = (int*)  (ws + 119552);     //    57,600 -> 177,152
    unsigned char* fgm = (unsigned char*)(ws + 177152);    // 14,400
    unsigned char* bgm = (unsigned char*)(ws + 191552);    // 14,400 -> 205,952
    float* pp        = (float*)(ws + 205952);     //   466,944 -> 672,896
    unsigned short* Vg  = (unsigned short*)(ws + 672896);   //  1,572,864 -> 2,245,760
    unsigned short* Qf  = (unsigned short*)(ws + 2245760);  //  7,372,800 -> 9,618,560
    unsigned short* wbuf = (unsigned short*)(ws + 9618560); // 22,118,400 -> 31,736,960
    float* wpart     = (float*)(ws + 31736960);   //   691,200 -> 32,428,160

    k_mask    <<<NB,               1024, 0, stream>>>(mask_q, fgm, bgm, bgsel, cnts);
    k_normpack<<<dim3(57, NB),     256, 0, stream>>>(feature, fgm, bgm, colnorm, Qf, pp);
    k_vg      <<<dim3(223, 1, NB), 256, 0, stream>>>(Qf, colnorm, cnts, bgsel, Vg,
                                                     pp, out, bgproto, wbuf, wpart);
    k_gemm2e  <<<dim3(29, 2, NB),  256, 0, stream>>>(wbuf, Vg, cnts, wpart, bgproto, out);
    // fallback path, active only for batches with M > MCAP
    k_attn    <<<dim3(225, NB),    256, 0, stream>>>(feature, colnorm, cnts, bgsel,
                                                     bgproto, out, 1);
  } else {
    // small-ws fallback: simple kernels, self-normalizing attention
    float* colnorm  = (float*)(ws + 0);
    float* bgproto  = (float*)(ws + 115200);
    int*   cnts    = (int*)  (ws + 119296);
    int*   bgsel    = (int*)  (ws + 119552);
    unsigned char* fgm = (unsigned char*)(ws + 177152);
    unsigned char* bgm = (unsigned char*)(ws + 191552);

    k_colnorm<<<dim3(15, NB), 256, 0, stream>>>(feature, colnorm);
    k_mask   <<<NB,           1024, 0, stream>>>(mask_q, fgm, bgm, bgsel, cnts);
    k_proto  <<<dim3(NC, NB), 256, 0, stream>>>(feature, fgm, bgm, cnts, out, bgproto);
    k_attn   <<<dim3(225, NB),256, 0, stream>>>(feature, colnorm, cnts, bgsel,
                                                bgproto, out, 0);
  }
}